// Round 4
// baseline (27.631 us; speedup 1.0000x reference)
//
#include <hip/hip_runtime.h>
#include <math.h>

// TransitionGNN: N=16384, K=32, N_OF=7, N_EF=1, H=1 -> all layers scalar.
// Wave-per-graph, 2 graphs per wave, software-pipelined:
//   load A (regs) -> pass1 A -> prefetch B (ef via global_load_lds, of/act
//   via regs) -> pass2 A + stores -> compute B from LDS/regs.
// Cross-lane: DPP adds for the 8-lane row reduce; tiny per-wave LDS arrays
// for hn/hn2 gathers (wave-synchronous). Nontemporal float4 output stores.

typedef float v4f __attribute__((ext_vector_type(4)));

#define DPP_ADD(p, ctrl)                                                  \
    ((p) + __int_as_float(__builtin_amdgcn_mov_dpp(                       \
               __float_as_int(p), (ctrl), 0xf, 0xf, true)))

__device__ __forceinline__ void glds16(const float* gsrc, float* ldst) {
    // size=16: global_load_lds_dwordx4. LDS dst = wave-uniform base
    // (+ lane*16 added by HW); global src is per-lane.
    __builtin_amdgcn_global_load_lds(
        (const __attribute__((address_space(1))) void*)gsrc,
        (__attribute__((address_space(3))) void*)ldst,
        16, 0, 0);
}

__global__ __launch_bounds__(256, 6) void gnn_fused_kernel(
    const float* __restrict__ of,    // (N,32,7)
    const float* __restrict__ ef,    // (N,32,32)
    const float* __restrict__ act,   // (N,7)
    const float* __restrict__ W_ni,  // (14,)
    const float* __restrict__ b_ni,  // (1,)
    const float* __restrict__ W_e,   // (3,)
    const float* __restrict__ b_e,   // (1,)
    const float* __restrict__ W_n,   // (1,)
    const float* __restrict__ b_n,   // (1,)
    const float* __restrict__ W_ef,  // (1,)
    const float* __restrict__ b_ef,  // (1,)
    float* __restrict__ out,         // (N,32,32)
    int Ntot, int halfN)
{
    const int wv = threadIdx.x >> 6;           // wave in block (0..3)
    const int l  = threadIdx.x & 63;           // lane
    const int nA = blockIdx.x * 4 + wv;        // first graph of this wave
    if (nA >= halfN) return;
    const int nB = nA + halfN;                 // second graph (wave-uniform)
    const bool hasB = (nB < Ntot);

    __shared__ __align__(16) float sh_hn[4][32];
    __shared__ __align__(16) float sh_hn2[4][32];
    __shared__ __align__(16) float sh_ef[4][1024];   // B-graph ef stage, 4KB/wave
    float* hn_lds  = sh_hn[wv];
    float* hn2_lds = sh_hn2[wv];
    float* efst    = sh_ef[wv];

    const int m     = l >> 3;        // row-group 0..7
    const int jbase = (l & 7) * 4;   // column base

    // Uniform scalar weights (s_load'd).
    const float we0 = W_e[0], we1 = W_e[1], we2 = W_e[2], be = b_e[0];
    const float wn  = W_n[0],  bn  = b_n[0];
    const float wef = W_ef[0], bef = b_ef[0];
    const float bni = b_ni[0];

    // ---- Graph A: all 16 ef loads + of/act, in registers ----
    const float* efpA = ef + (size_t)nA * 1024 + l * 4;
    const float4 a0 = *reinterpret_cast<const float4*>(efpA);
    const float4 a1 = *reinterpret_cast<const float4*>(efpA + 256);
    const float4 a2 = *reinterpret_cast<const float4*>(efpA + 512);
    const float4 a3 = *reinterpret_cast<const float4*>(efpA + 768);

    float hnA;
    {
        const float* ofp = of + ((size_t)nA * 32 + (l & 31)) * 7;
        const float* ap  = act + (size_t)nA * 7;
        float s = bni;
        #pragma unroll
        for (int f = 0; f < 7; ++f) s = fmaf(ofp[f], W_ni[f], s);
        #pragma unroll
        for (int f = 0; f < 7; ++f) s = fmaf(ap[f], W_ni[7 + f], s);
        hnA = s;
    }

    // pass1: edge pass + row-sum + node update; leaves g0..g3 (rows q*8+m)
    // and gj (cols jbase..+3) for pass2.
    auto pass1 = [&](const float4& e0, const float4& e1, const float4& e2,
                     const float4& e3, float hn_own,
                     float& g0, float& g1, float& g2, float& g3, float4& gj) {
        hn_lds[l & 31] = hn_own;               // 2-way dup write
        __builtin_amdgcn_wave_barrier();
        const float4 hj = *reinterpret_cast<const float4*>(&hn_lds[jbase]);
        const float hi0 = hn_lds[m];
        const float hi1 = hn_lds[m + 8];
        const float hi2 = hn_lds[m + 16];
        const float hi3 = hn_lds[m + 24];

        auto rowsum = [&](const float4& e, float hi) {
            const float a = fmaf(we0, hi, be);
            float p = fmaxf(fmaf(we2, e.x, fmaf(we1, hj.x, a)), 0.f)
                    + fmaxf(fmaf(we2, e.y, fmaf(we1, hj.y, a)), 0.f)
                    + fmaxf(fmaf(we2, e.z, fmaf(we1, hj.z, a)), 0.f)
                    + fmaxf(fmaf(we2, e.w, fmaf(we1, hj.w, a)), 0.f);
            p = DPP_ADD(p, 0xB1);   // quad_perm xor1
            p = DPP_ADD(p, 0x4E);   // quad_perm xor2
            p = DPP_ADD(p, 0x141);  // row_half_mirror (xor4 in 8-grp)
            return p;               // row sum in all 8 lanes of group m
        };
        g0 = fmaxf(fmaf(wn, rowsum(e0, hi0), bn), 0.f);
        g1 = fmaxf(fmaf(wn, rowsum(e1, hi1), bn), 0.f);
        g2 = fmaxf(fmaf(wn, rowsum(e2, hi2), bn), 0.f);
        g3 = fmaxf(fmaf(wn, rowsum(e3, hi3), bn), 0.f);

        if ((l & 7) == 0) {
            hn2_lds[m]      = g0;
            hn2_lds[m + 8]  = g1;
            hn2_lds[m + 16] = g2;
            hn2_lds[m + 24] = g3;
        }
        __builtin_amdgcn_wave_barrier();
        gj = *reinterpret_cast<const float4*>(&hn2_lds[jbase]);
    };

    auto pass2 = [&](const float4& e0, const float4& e1, const float4& e2,
                     const float4& e3, float g0, float g1, float g2, float g3,
                     const float4& gj, float* outp) {
        auto edge2 = [&](const float4& e, float gi, float* dst) {
            const float a = fmaf(we0, gi, be);
            v4f o;
            {
                float v = fmaxf(fmaf(we2, e.x, fmaf(we1, gj.x, a)), 0.f);
                v = fmaxf(fmaf(wef, v, bef), 0.f);
                o.x = __builtin_amdgcn_rcpf(1.f + __builtin_amdgcn_exp2f(v * -1.44269504089f));
            }
            {
                float v = fmaxf(fmaf(we2, e.y, fmaf(we1, gj.y, a)), 0.f);
                v = fmaxf(fmaf(wef, v, bef), 0.f);
                o.y = __builtin_amdgcn_rcpf(1.f + __builtin_amdgcn_exp2f(v * -1.44269504089f));
            }
            {
                float v = fmaxf(fmaf(we2, e.z, fmaf(we1, gj.z, a)), 0.f);
                v = fmaxf(fmaf(wef, v, bef), 0.f);
                o.z = __builtin_amdgcn_rcpf(1.f + __builtin_amdgcn_exp2f(v * -1.44269504089f));
            }
            {
                float v = fmaxf(fmaf(we2, e.w, fmaf(we1, gj.w, a)), 0.f);
                v = fmaxf(fmaf(wef, v, bef), 0.f);
                o.w = __builtin_amdgcn_rcpf(1.f + __builtin_amdgcn_exp2f(v * -1.44269504089f));
            }
            __builtin_nontemporal_store(o, (v4f*)dst);
        };
        edge2(e0, g0, outp);
        edge2(e1, g1, outp + 256);
        edge2(e2, g2, outp + 512);
        edge2(e3, g3, outp + 768);
    };

    // ---- A pass1 ----
    float g0, g1, g2, g3;
    float4 gjA;
    pass1(a0, a1, a2, a3, hnA, g0, g1, g2, g3, gjA);

    // ---- Prefetch graph B: ef -> LDS (glds), of/act -> regs ----
    float ofb[7], actb[7];
    if (hasB) {
        const float* efpB = ef + (size_t)nB * 1024 + l * 4;
        glds16(efpB,       &efst[0]);
        glds16(efpB + 256, &efst[256]);
        glds16(efpB + 512, &efst[512]);
        glds16(efpB + 768, &efst[768]);
        __builtin_amdgcn_sched_barrier(0);   // glds issue before of/act loads
        const float* ofpB = of + ((size_t)nB * 32 + (l & 31)) * 7;
        const float* apB  = act + (size_t)nB * 7;
        #pragma unroll
        for (int f = 0; f < 7; ++f) ofb[f] = ofpB[f];
        #pragma unroll
        for (int f = 0; f < 7; ++f) actb[f] = apB[f];
        __builtin_amdgcn_sched_barrier(0);   // loads issue before pass2A stores
    }

    // ---- A pass2 + stores (covers B's load latency) ----
    pass2(a0, a1, a2, a3, g0, g1, g2, g3, gjA, out + (size_t)nA * 1024 + l * 4);

    // ---- Graph B ----
    if (hasB) {
        float hnB = bni;
        #pragma unroll
        for (int f = 0; f < 7; ++f) hnB = fmaf(ofb[f], W_ni[f], hnB);
        #pragma unroll
        for (int f = 0; f < 7; ++f) hnB = fmaf(actb[f], W_ni[7 + f], hnB);

        // Drain everything except the 4 youngest vmem ops (= A's stores):
        // glds + of/act loads are older, so this guarantees the LDS stage
        // is complete before we ds_read it.
        asm volatile("s_waitcnt vmcnt(4)" ::: "memory");
        const float4 b0 = *reinterpret_cast<const float4*>(&efst[l * 4]);
        const float4 b1 = *reinterpret_cast<const float4*>(&efst[256 + l * 4]);
        const float4 b2 = *reinterpret_cast<const float4*>(&efst[512 + l * 4]);
        const float4 b3 = *reinterpret_cast<const float4*>(&efst[768 + l * 4]);

        float4 gjB;
        pass1(b0, b1, b2, b3, hnB, g0, g1, g2, g3, gjB);
        pass2(b0, b1, b2, b3, g0, g1, g2, g3, gjB, out + (size_t)nB * 1024 + l * 4);
    }
}

extern "C" void kernel_launch(void* const* d_in, const int* in_sizes, int n_in,
                              void* d_out, int out_size, void* d_ws, size_t ws_size,
                              hipStream_t stream) {
    const float* of   = (const float*)d_in[0];
    const float* ef   = (const float*)d_in[1];
    const float* act  = (const float*)d_in[2];
    const float* W_ni = (const float*)d_in[3];
    const float* b_ni = (const float*)d_in[4];
    const float* b_e_ = (const float*)d_in[6];
    const float* W_e  = (const float*)d_in[5];
    const float* W_n  = (const float*)d_in[7];
    const float* b_n  = (const float*)d_in[8];
    const float* W_ef = (const float*)d_in[9];
    const float* b_ef = (const float*)d_in[10];
    float* out = (float*)d_out;

    const int N = in_sizes[2] / 7;     // action is (N,7)
    const int halfN = (N + 1) / 2;     // graphs per pipeline slot
    const int blocks = (halfN + 3) / 4;  // 4 waves per block, 2 graphs per wave
    gnn_fused_kernel<<<blocks, 256, 0, stream>>>(
        of, ef, act, W_ni, b_ni, W_e, b_e_, W_n, b_n, W_ef, b_ef, out, N, halfN);
}